// Round 1
// 354.663 us; speedup vs baseline: 1.0536x; 1.0536x over previous
//
#include <hip/hip_runtime.h>
#include <stdint.h>

typedef __bf16 bf16x8 __attribute__((ext_vector_type(8)));
typedef float floatx4 __attribute__((ext_vector_type(4)));
typedef unsigned short u16;

__device__ __forceinline__ float bf2f(u16 u) {
    union { uint32_t i; float f; } v; v.i = ((uint32_t)u) << 16; return v.f;
}
__device__ __forceinline__ u16 f2bf(float f) {
    union { float f; uint32_t i; } v; v.f = f;
    uint32_t r = v.i + 0x7fffu + ((v.i >> 16) & 1u);
    return (u16)(r >> 16);
}

// async global->LDS, 16B per lane. LDS dest must be wave-uniform base; HW adds lane*16.
__device__ __forceinline__ void gload_lds16(const u16* g, u16* l) {
    __builtin_amdgcn_global_load_lds(
        (const __attribute__((address_space(1))) void*)g,
        (__attribute__((address_space(3))) void*)l,
        16, 0, 0);
}

#define TM 128
#define TN 128
#define BK 64

// C = A[M,K] @ Bt[N,K]^T + bias[N] (+ addsrc); A,Bt,addsrc bf16; bias fp32; fp32 accum.
// Output: bf16 to C16 (if non-null) else fp32 to C32.
// m97 structure: linear LDS [128][64], global_load_lds width=16, 2 barriers/K-step.
// In-kernel bijective XCD-chunk swizzle (all launches have nwg % 8 == 0).
__global__ __launch_bounds__(256) void gemm_bt_kernel(
    const u16* __restrict__ A, int lda,
    const u16* __restrict__ Bt,
    const float* __restrict__ bias,
    const u16* __restrict__ addsrc, int ldadd,
    u16* __restrict__ C16, float* __restrict__ C32, int ldc,
    int K)
{
    __shared__ __attribute__((aligned(16))) u16 lsA[TM * BK];  // 16 KiB, linear (gload_lds needs it)
    __shared__ __attribute__((aligned(16))) u16 lsB[TN * BK];  // 16 KiB
    const int tid  = threadIdx.x;
    const int wave = tid >> 6;
    const int lane = tid & 63;
    const int quad = lane >> 4;
    const int l16  = lane & 15;
    const int wm = wave >> 1, wn = wave & 1;

    // XCD-aware chunked swizzle: consecutive tiles (sharing an A row-panel) land on one XCD's L2.
    const int gx   = gridDim.x;
    const int nwg  = gx * gridDim.y;
    const int wgid = blockIdx.y * gx + blockIdx.x;
    const int cpx  = nwg >> 3;                       // nwg % 8 == 0 guaranteed by launches below
    const int swz  = (wgid & 7) * cpx + (wgid >> 3);
    const int row0 = (swz / gx) * TM;
    const int col0 = (swz % gx) * TN;

    floatx4 acc[4][4] = {};

    // per-lane global source bases for the 4 staging chunks of each matrix
    // chunk cc = wave*4+c covers rows [cc*8, cc*8+8); lane l -> row cc*8+(l>>3), k-off (l&7)*8
    const int rsub = lane >> 3;
    const int ksub = (lane & 7) * 8;
    const u16* aptr[4]; const u16* bptr[4];
#pragma unroll
    for (int c = 0; c < 4; ++c) {
        const int cc = wave * 4 + c;
        aptr[c] = A  + (size_t)(row0 + cc * 8 + rsub) * lda + ksub;
        bptr[c] = Bt + (size_t)(col0 + cc * 8 + rsub) * K   + ksub;
    }

    for (int kt = 0; kt < K; kt += BK) {
#pragma unroll
        for (int c = 0; c < 4; ++c) {
            const int cc = wave * 4 + c;
            gload_lds16(aptr[c] + kt, &lsA[cc * 512]);   // 512 u16 = 1024 B per wave-chunk
            gload_lds16(bptr[c] + kt, &lsB[cc * 512]);
        }
        __syncthreads();   // compiler emits s_waitcnt vmcnt(0) before s_barrier -> LDS valid
#pragma unroll
        for (int ks = 0; ks < 2; ++ks) {
            const int cidx = ks * 4 + quad;
            bf16x8 af[4], bfr[4];
#pragma unroll
            for (int i = 0; i < 4; ++i) {
                int m = wm * 64 + i * 16 + l16;
                af[i] = *(const bf16x8*)&lsA[m * BK + cidx * 8];
            }
#pragma unroll
            for (int j = 0; j < 4; ++j) {
                int n = wn * 64 + j * 16 + l16;
                bfr[j] = *(const bf16x8*)&lsB[n * BK + cidx * 8];
            }
#pragma unroll
            for (int i = 0; i < 4; ++i)
#pragma unroll
                for (int j = 0; j < 4; ++j)
                    acc[i][j] = __builtin_amdgcn_mfma_f32_16x16x32_bf16(af[i], bfr[j], acc[i][j], 0, 0, 0);
        }
        __syncthreads();
    }

    // epilogue: C/D layout col=lane&15, row=quad*4+reg  (validated vs VALU GEMM in R3/R4)
#pragma unroll
    for (int j = 0; j < 4; ++j) {
        int col = col0 + wn * 64 + j * 16 + l16;
        float bv = bias[col];
#pragma unroll
        for (int i = 0; i < 4; ++i) {
            int rowb = row0 + wm * 64 + i * 16 + quad * 4;
#pragma unroll
            for (int t = 0; t < 4; ++t) {
                float v = acc[i][j][t] + bv;
                if (addsrc) v += bf2f(addsrc[(size_t)(rowb + t) * ldadd + col]);
                if (C16) C16[(size_t)(rowb + t) * ldc + col] = f2bf(v);
                else     C32[(size_t)(rowb + t) * ldc + col] = v;
            }
        }
    }
}

// Per row of QK[M,1024]: l2-normalize cols 0..511 (Q) and 512..1023 (K) separately,
// write back, accumulate g[b,:] += Qn row. 32 rows per block, 256 threads.
__global__ __launch_bounds__(256) void norm_g_kernel(u16* __restrict__ QK, float* __restrict__ g)
{
    __shared__ float wsum[2][4];
    const int tid = threadIdx.x;
    const int wave = tid >> 6, lane = tid & 63;
    const int row_base = blockIdx.x * 32;
    const int batch = row_base >> 12; // 4096 rows per batch
    float gl0 = 0.f, gl1 = 0.f, gl2 = 0.f, gl3 = 0.f;
    for (int rr = 0; rr < 32; ++rr) {
        const size_t base = (size_t)(row_base + rr) * 1024 + tid * 4;
        ushort4 u = *(const ushort4*)(QK + base);
        float v0 = bf2f(u.x), v1 = bf2f(u.y), v2 = bf2f(u.z), v3 = bf2f(u.w);
        float ss = v0 * v0 + v1 * v1 + v2 * v2 + v3 * v3;
#pragma unroll
        for (int off = 32; off > 0; off >>= 1) ss += __shfl_xor(ss, off);
        if (lane == 0) wsum[rr & 1][wave] = ss;
        __syncthreads();
        float s2 = (wave < 2) ? (wsum[rr & 1][0] + wsum[rr & 1][1])
                              : (wsum[rr & 1][2] + wsum[rr & 1][3]);
        float rs = rsqrtf(fmaxf(s2, 1e-12f));
        v0 *= rs; v1 *= rs; v2 *= rs; v3 *= rs;
        ushort4 o;
        o.x = f2bf(v0); o.y = f2bf(v1); o.z = f2bf(v2); o.w = f2bf(v3);
        *(ushort4*)(QK + base) = o;
        if (wave < 2) { gl0 += v0; gl1 += v1; gl2 += v2; gl3 += v3; }
    }
    if (wave < 2) {
        int d = batch * 512 + tid * 4;
        atomicAdd(&g[d + 0], gl0);
        atomicAdd(&g[d + 1], gl1);
        atomicAdd(&g[d + 2], gl2);
        atomicAdd(&g[d + 3], gl3);
    }
}

// Kn *= g[b] (in place, K half of QK)
__global__ __launch_bounds__(256) void scale_k_kernel(u16* __restrict__ QK, const float* __restrict__ g)
{
    size_t idx = ((size_t)blockIdx.x * 256 + threadIdx.x) * 4; // over M*512
    int row = (int)(idx >> 9);
    int d = (int)(idx & 511);
    int batch = row >> 12;
    u16* p = QK + (size_t)row * 1024 + 512 + d;
    ushort4 u = *(const ushort4*)p;
    float4 gv = *(const float4*)(g + batch * 512 + d);
    ushort4 o;
    o.x = f2bf(bf2f(u.x) * gv.x);
    o.y = f2bf(bf2f(u.y) * gv.y);
    o.z = f2bf(bf2f(u.z) * gv.z);
    o.w = f2bf(bf2f(u.w) * gv.w);
    *(ushort4*)p = o;
}

// x (fp32) -> bf16
__global__ __launch_bounds__(256) void convert_x_kernel(const float* __restrict__ x, u16* __restrict__ xb)
{
    size_t i = ((size_t)blockIdx.x * 256 + threadIdx.x) * 4;
    float4 v = *(const float4*)(x + i);
    ushort4 o;
    o.x = f2bf(v.x); o.y = f2bf(v.y); o.z = f2bf(v.z); o.w = f2bf(v.w);
    *(ushort4*)(xb + i) = o;
}

// LDS-tiled transpose of all four 512x512 fp32 weights -> bf16 Bt[n*512+k] = W[k*512+n].
// Coalesced on both sides; tile stride 34 u16 => bank-conflict-free column reads.
__global__ __launch_bounds__(256) void transpose4_kernel(
    const float* __restrict__ w0, const float* __restrict__ w1,
    const float* __restrict__ w2, const float* __restrict__ w3,
    u16* __restrict__ d0, u16* __restrict__ d1,
    u16* __restrict__ d2, u16* __restrict__ d3)
{
    __shared__ u16 tile[32][34];
    const int which = blockIdx.x >> 8;
    const float* W = (which == 0) ? w0 : (which == 1) ? w1 : (which == 2) ? w2 : w3;
    u16* Bt = (which == 0) ? d0 : (which == 1) ? d1 : (which == 2) ? d2 : d3;
    const int bid = blockIdx.x & 255;
    const int tk = bid & 15;   // 32-wide tile index along k
    const int tn = bid >> 4;   // 32-wide tile index along n
    const int c  = threadIdx.x & 31;
    const int r0 = threadIdx.x >> 5;
#pragma unroll
    for (int i = 0; i < 4; ++i) {
        int r = r0 + i * 8;
        tile[r][c] = f2bf(W[(size_t)(tk * 32 + r) * 512 + tn * 32 + c]);  // coalesced read
    }
    __syncthreads();
#pragma unroll
    for (int i = 0; i < 4; ++i) {
        int r = r0 + i * 8;
        Bt[(size_t)(tn * 32 + r) * 512 + tk * 32 + c] = tile[c][r];       // coalesced write
    }
}

__global__ __launch_bounds__(256) void bias_cat_kernel(const float* __restrict__ bq, const float* __restrict__ bk,
                                                       float* __restrict__ b)
{
    int id = blockIdx.x * 256 + threadIdx.x; // 0..1023
    b[id] = (id < 512) ? bq[id] : bk[id - 512];
}

extern "C" void kernel_launch(void* const* d_in, const int* in_sizes, int n_in,
                              void* d_out, int out_size, void* d_ws, size_t ws_size,
                              hipStream_t stream)
{
    const float* x  = (const float*)d_in[0];
    const float* wq = (const float*)d_in[1];
    const float* bq = (const float*)d_in[2];
    const float* wk = (const float*)d_in[3];
    const float* bk = (const float*)d_in[4];
    const float* wp = (const float*)d_in[5];
    const float* bp = (const float*)d_in[6];
    const float* wf = (const float*)d_in[7];
    const float* bf = (const float*)d_in[8];
    // d_in[9] = w_g unused: softmax over a size-1 axis is identically 1.

    char* ws = (char*)d_ws;
    // xb aliased with T: xb dead after GEMM1, T born at GEMM2.
    u16*   xb     = (u16*)(ws);                 // 32768 x 512 bf16 = 32 MiB
    u16*   T      = (u16*)(ws);                 // 32768 x 512 bf16 (alias)
    u16*   QK     = (u16*)(ws + 33554432);      // 32768 x 1024 bf16 = 64 MiB
    u16*   Bt1    = (u16*)(ws + 100663296);     // 1024 x 512 bf16 = 1 MiB
    u16*   BtP    = (u16*)(ws + 101711872);     // 512 x 512
    u16*   BtF    = (u16*)(ws + 102236160);     // 512 x 512
    float* biasQK = (float*)(ws + 102760448);   // 1024 fp32
    float* g      = (float*)(ws + 102764544);   // 8 x 512 fp32

    hipMemsetAsync(g, 0, 8 * 512 * sizeof(float), stream);
    convert_x_kernel<<<16384, 256, 0, stream>>>(x, xb);
    bias_cat_kernel<<<4, 256, 0, stream>>>(bq, bk, biasQK);
    transpose4_kernel<<<1024, 256, 0, stream>>>(wq, wk, wp, wf,
                                                Bt1, Bt1 + 512 * 512, BtP, BtF);

    // QK = x @ [wq|wk] + [bq|bk]          (bf16 out)   nwg = 2048, %8==0
    gemm_bt_kernel<<<dim3(8, 256), 256, 0, stream>>>(xb, 512, Bt1, biasQK, nullptr, 0, QK, nullptr, 1024, 512);
    // normalize rows of Q,K halves; g[b] = sum_n Qn
    norm_g_kernel<<<1024, 256, 0, stream>>>(QK, g);
    // Kg = Kn * g[b]
    scale_k_kernel<<<16384, 256, 0, stream>>>(QK, g);
    // T = Kg @ wp + bp + Qn               (bf16 out)   nwg = 1024, %8==0
    gemm_bt_kernel<<<dim3(4, 256), 256, 0, stream>>>(QK + 512, 1024, BtP, bp, QK, 1024, T, nullptr, 512, 512);
    // out = T @ wf + bf                   (fp32 out -> d_out)  nwg = 1024, %8==0
    gemm_bt_kernel<<<dim3(4, 256), 256, 0, stream>>>(T, 512, BtF, bf, nullptr, 0, nullptr, (float*)d_out, 512, 512);
}

// Round 2
// 323.466 us; speedup vs baseline: 1.1552x; 1.0964x over previous
//
#include <hip/hip_runtime.h>
#include <stdint.h>

typedef __bf16 bf16x8 __attribute__((ext_vector_type(8)));
typedef float floatx4 __attribute__((ext_vector_type(4)));
typedef unsigned short u16;
typedef u16 u16x8 __attribute__((ext_vector_type(8)));

__device__ __forceinline__ float bf2f(u16 u) {
    union { uint32_t i; float f; } v; v.i = ((uint32_t)u) << 16; return v.f;
}
__device__ __forceinline__ u16 f2bf(float f) {
    union { float f; uint32_t i; } v; v.f = f;
    uint32_t r = v.i + 0x7fffu + ((v.i >> 16) & 1u);
    return (u16)(r >> 16);
}

// async global->LDS, 16B per lane. LDS dest must be wave-uniform base; HW adds lane*16.
__device__ __forceinline__ void gload_lds16(const u16* g, u16* l) {
    __builtin_amdgcn_global_load_lds(
        (const __attribute__((address_space(1))) void*)g,
        (__attribute__((address_space(3))) void*)l,
        16, 0, 0);
}

#define TM 128
#define TN 128
#define BK 64
#define RSTR 132  // repack tile row stride (u16): conflict-free quad writes, 8B-aligned b64 reads

// C = A[M,K] @ Bt[N,K]^T + bias[N] (+ addsrc); A,Bt,addsrc bf16; bias fp32; fp32 accum.
// Output: bf16 to C16 (if non-null, LDS-repacked coalesced stores) else fp32 to C32 (scalar dwords).
// m97 structure + both-sides XOR swizzle (rule 21): linear LDS dest for global_load_lds,
// inverse-swizzled per-lane GLOBAL source, swizzled ds_read. 16-way -> 8-way bank conflicts.
__global__ __launch_bounds__(256) void gemm_bt_kernel(
    const u16* __restrict__ A, int lda,
    const u16* __restrict__ Bt,
    const float* __restrict__ bias,
    const u16* __restrict__ addsrc, int ldadd,
    u16* __restrict__ C16, float* __restrict__ C32, int ldc,
    int K)
{
    // staging: lsA = lds[0..8192), lsB = lds[8192..16384); repack tile reuses lds[0..16896)
    __shared__ __attribute__((aligned(16))) u16 lds[TM * RSTR];  // 33792 B >= 2*8192*2
    u16* lsA = lds;
    u16* lsB = lds + TM * BK;
    const int tid  = threadIdx.x;
    const int wave = tid >> 6;
    const int lane = tid & 63;
    const int quad = lane >> 4;
    const int l16  = lane & 15;
    const int wm = wave >> 1, wn = wave & 1;

    // XCD-aware chunked swizzle (all launches have nwg % 8 == 0)
    const int gx   = gridDim.x;
    const int nwg  = gx * gridDim.y;
    const int wgid = blockIdx.y * gx + blockIdx.x;
    const int cpx  = nwg >> 3;
    const int swz  = (wgid & 7) * cpx + (wgid >> 3);
    const int row0 = (swz / gx) * TM;
    const int col0 = (swz % gx) * TN;

    floatx4 acc[4][4] = {};

    // staging chunk cc = wave*4+c covers rows [cc*8, cc*8+8); lane l -> row cc*8+(l>>3).
    // K-offset is XOR-swizzled by row&7 (= l>>3) so that LDS position (r, pg) holds
    // logical k-group pg ^ (r&7)  => linear gload_lds dest + swizzled ds_read works.
    const int rsub = lane >> 3;
    const int ksub = ((lane & 7) ^ rsub) << 3;  // u16 units, 0..56, 16B aligned
    const u16* aptr[4]; const u16* bptr[4];
#pragma unroll
    for (int c = 0; c < 4; ++c) {
        const int cc = wave * 4 + c;
        aptr[c] = A  + (size_t)(row0 + cc * 8 + rsub) * lda + ksub;
        bptr[c] = Bt + (size_t)(col0 + cc * 8 + rsub) * K   + ksub;
    }

    for (int kt = 0; kt < K; kt += BK) {
#pragma unroll
        for (int c = 0; c < 4; ++c) {
            const int cc = wave * 4 + c;
            gload_lds16(aptr[c] + kt, &lsA[cc * 512]);
            gload_lds16(bptr[c] + kt, &lsB[cc * 512]);
        }
        __syncthreads();
#pragma unroll
        for (int ks = 0; ks < 2; ++ks) {
            const int cidx = ks * 4 + quad;
            const int pgo = ((cidx ^ (l16 & 7)) << 3);  // swizzled k-group offset in row
            bf16x8 af[4], bfr[4];
#pragma unroll
            for (int i = 0; i < 4; ++i) {
                int m = wm * 64 + i * 16 + l16;
                af[i] = *(const bf16x8*)&lsA[m * BK + pgo];
            }
#pragma unroll
            for (int j = 0; j < 4; ++j) {
                int n = wn * 64 + j * 16 + l16;
                bfr[j] = *(const bf16x8*)&lsB[n * BK + pgo];
            }
#pragma unroll
            for (int i = 0; i < 4; ++i)
#pragma unroll
                for (int j = 0; j < 4; ++j)
                    acc[i][j] = __builtin_amdgcn_mfma_f32_16x16x32_bf16(af[i], bfr[j], acc[i][j], 0, 0, 0);
        }
        __syncthreads();
    }

    // epilogue. C/D layout: col=lane&15, row=quad*4+reg (validated R3/R4 of prior session).
    if (C16) {
        // stage into [128][RSTR] u16 tile (aliases staging LDS; safe after final barrier),
        // then 8 x global_store_dwordx4 per thread, 256B-contiguous per 16 lanes.
#pragma unroll
        for (int j = 0; j < 4; ++j) {
            int col = col0 + wn * 64 + j * 16 + l16;
            float bv = bias[col];
            int tcol = wn * 64 + j * 16 + l16;
#pragma unroll
            for (int i = 0; i < 4; ++i) {
                int trow = wm * 64 + i * 16 + quad * 4;
                int rowb = row0 + trow;
#pragma unroll
                for (int t = 0; t < 4; ++t) {
                    float v = acc[i][j][t] + bv;
                    if (addsrc) v += bf2f(addsrc[(size_t)(rowb + t) * ldadd + col]);
                    lds[(trow + t) * RSTR + tcol] = f2bf(v);
                }
            }
        }
        __syncthreads();
#pragma unroll
        for (int c = 0; c < 8; ++c) {
            int r  = c * 16 + (tid >> 4);       // 0..127
            int cu = (tid & 15) * 8;            // u16 col, 16B aligned
            ushort4 lo = *(const ushort4*)&lds[r * RSTR + cu];
            ushort4 hi = *(const ushort4*)&lds[r * RSTR + cu + 4];
            u16x8 o;
            o[0] = lo.x; o[1] = lo.y; o[2] = lo.z; o[3] = lo.w;
            o[4] = hi.x; o[5] = hi.y; o[6] = hi.z; o[7] = hi.w;
            *(u16x8*)&C16[(size_t)(row0 + r) * ldc + col0 + cu] = o;
        }
    } else {
        // fp32 path: scalar dword stores (64B/quad segments — acceptable)
#pragma unroll
        for (int j = 0; j < 4; ++j) {
            int col = col0 + wn * 64 + j * 16 + l16;
            float bv = bias[col];
#pragma unroll
            for (int i = 0; i < 4; ++i) {
                int rowb = row0 + wm * 64 + i * 16 + quad * 4;
#pragma unroll
                for (int t = 0; t < 4; ++t) {
                    float v = acc[i][j][t] + bv;
                    C32[(size_t)(rowb + t) * ldc + col0 + wn * 64 + j * 16 + l16] = v;
                    (void)col;
                }
            }
        }
    }
}

// Per row of QK[M,1024]: l2-normalize cols 0..511 (Q) and 512..1023 (K) separately,
// write back, accumulate g[b,:] += Qn row. 32 rows per block, 256 threads.
__global__ __launch_bounds__(256) void norm_g_kernel(u16* __restrict__ QK, float* __restrict__ g)
{
    __shared__ float wsum[2][4];
    const int tid = threadIdx.x;
    const int wave = tid >> 6, lane = tid & 63;
    const int row_base = blockIdx.x * 32;
    const int batch = row_base >> 12; // 4096 rows per batch
    float gl0 = 0.f, gl1 = 0.f, gl2 = 0.f, gl3 = 0.f;
    for (int rr = 0; rr < 32; ++rr) {
        const size_t base = (size_t)(row_base + rr) * 1024 + tid * 4;
        ushort4 u = *(const ushort4*)(QK + base);
        float v0 = bf2f(u.x), v1 = bf2f(u.y), v2 = bf2f(u.z), v3 = bf2f(u.w);
        float ss = v0 * v0 + v1 * v1 + v2 * v2 + v3 * v3;
#pragma unroll
        for (int off = 32; off > 0; off >>= 1) ss += __shfl_xor(ss, off);
        if (lane == 0) wsum[rr & 1][wave] = ss;
        __syncthreads();
        float s2 = (wave < 2) ? (wsum[rr & 1][0] + wsum[rr & 1][1])
                              : (wsum[rr & 1][2] + wsum[rr & 1][3]);
        float rs = rsqrtf(fmaxf(s2, 1e-12f));
        v0 *= rs; v1 *= rs; v2 *= rs; v3 *= rs;
        ushort4 o;
        o.x = f2bf(v0); o.y = f2bf(v1); o.z = f2bf(v2); o.w = f2bf(v3);
        *(ushort4*)(QK + base) = o;
        if (wave < 2) { gl0 += v0; gl1 += v1; gl2 += v2; gl3 += v3; }
    }
    if (wave < 2) {
        int d = batch * 512 + tid * 4;
        atomicAdd(&g[d + 0], gl0);
        atomicAdd(&g[d + 1], gl1);
        atomicAdd(&g[d + 2], gl2);
        atomicAdd(&g[d + 3], gl3);
    }
}

// Kn *= g[b] (in place, K half of QK)
__global__ __launch_bounds__(256) void scale_k_kernel(u16* __restrict__ QK, const float* __restrict__ g)
{
    size_t idx = ((size_t)blockIdx.x * 256 + threadIdx.x) * 4; // over M*512
    int row = (int)(idx >> 9);
    int d = (int)(idx & 511);
    int batch = row >> 12;
    u16* p = QK + (size_t)row * 1024 + 512 + d;
    ushort4 u = *(const ushort4*)p;
    float4 gv = *(const float4*)(g + batch * 512 + d);
    ushort4 o;
    o.x = f2bf(bf2f(u.x) * gv.x);
    o.y = f2bf(bf2f(u.y) * gv.y);
    o.z = f2bf(bf2f(u.z) * gv.z);
    o.w = f2bf(bf2f(u.w) * gv.w);
    *(ushort4*)p = o;
}

// x (fp32) -> bf16
__global__ __launch_bounds__(256) void convert_x_kernel(const float* __restrict__ x, u16* __restrict__ xb)
{
    size_t i = ((size_t)blockIdx.x * 256 + threadIdx.x) * 4;
    float4 v = *(const float4*)(x + i);
    ushort4 o;
    o.x = f2bf(v.x); o.y = f2bf(v.y); o.z = f2bf(v.z); o.w = f2bf(v.w);
    *(ushort4*)(xb + i) = o;
}

// LDS-tiled transpose of all four 512x512 fp32 weights -> bf16 Bt[n*512+k] = W[k*512+n].
__global__ __launch_bounds__(256) void transpose4_kernel(
    const float* __restrict__ w0, const float* __restrict__ w1,
    const float* __restrict__ w2, const float* __restrict__ w3,
    u16* __restrict__ d0, u16* __restrict__ d1,
    u16* __restrict__ d2, u16* __restrict__ d3)
{
    __shared__ u16 tile[32][34];
    const int which = blockIdx.x >> 8;
    const float* W = (which == 0) ? w0 : (which == 1) ? w1 : (which == 2) ? w2 : w3;
    u16* Bt = (which == 0) ? d0 : (which == 1) ? d1 : (which == 2) ? d2 : d3;
    const int bid = blockIdx.x & 255;
    const int tk = bid & 15;
    const int tn = bid >> 4;
    const int c  = threadIdx.x & 31;
    const int r0 = threadIdx.x >> 5;
#pragma unroll
    for (int i = 0; i < 4; ++i) {
        int r = r0 + i * 8;
        tile[r][c] = f2bf(W[(size_t)(tk * 32 + r) * 512 + tn * 32 + c]);
    }
    __syncthreads();
#pragma unroll
    for (int i = 0; i < 4; ++i) {
        int r = r0 + i * 8;
        Bt[(size_t)(tn * 32 + r) * 512 + tk * 32 + c] = tile[c][r];
    }
}

__global__ __launch_bounds__(256) void bias_cat_kernel(const float* __restrict__ bq, const float* __restrict__ bk,
                                                       float* __restrict__ b)
{
    int id = blockIdx.x * 256 + threadIdx.x; // 0..1023
    b[id] = (id < 512) ? bq[id] : bk[id - 512];
}

extern "C" void kernel_launch(void* const* d_in, const int* in_sizes, int n_in,
                              void* d_out, int out_size, void* d_ws, size_t ws_size,
                              hipStream_t stream)
{
    const float* x  = (const float*)d_in[0];
    const float* wq = (const float*)d_in[1];
    const float* bq = (const float*)d_in[2];
    const float* wk = (const float*)d_in[3];
    const float* bk = (const float*)d_in[4];
    const float* wp = (const float*)d_in[5];
    const float* bp = (const float*)d_in[6];
    const float* wf = (const float*)d_in[7];
    const float* bf = (const float*)d_in[8];
    // d_in[9] = w_g unused: softmax over a size-1 axis is identically 1.

    char* ws = (char*)d_ws;
    u16*   xb     = (u16*)(ws);                 // 32768 x 512 bf16 = 32 MiB
    u16*   T      = (u16*)(ws);                 // alias: xb dead after GEMM1
    u16*   QK     = (u16*)(ws + 33554432);      // 32768 x 1024 bf16 = 64 MiB
    u16*   Bt1    = (u16*)(ws + 100663296);     // 1024 x 512 bf16
    u16*   BtP    = (u16*)(ws + 101711872);     // 512 x 512
    u16*   BtF    = (u16*)(ws + 102236160);     // 512 x 512
    float* biasQK = (float*)(ws + 102760448);   // 1024 fp32
    float* g      = (float*)(ws + 102764544);   // 8 x 512 fp32

    hipMemsetAsync(g, 0, 8 * 512 * sizeof(float), stream);
    convert_x_kernel<<<16384, 256, 0, stream>>>(x, xb);
    bias_cat_kernel<<<4, 256, 0, stream>>>(bq, bk, biasQK);
    transpose4_kernel<<<1024, 256, 0, stream>>>(wq, wk, wp, wf,
                                                Bt1, Bt1 + 512 * 512, BtP, BtF);

    // QK = x @ [wq|wk] + [bq|bk]          (bf16 out)   nwg = 2048
    gemm_bt_kernel<<<dim3(8, 256), 256, 0, stream>>>(xb, 512, Bt1, biasQK, nullptr, 0, QK, nullptr, 1024, 512);
    norm_g_kernel<<<1024, 256, 0, stream>>>(QK, g);
    scale_k_kernel<<<16384, 256, 0, stream>>>(QK, g);
    // T = Kg @ wp + bp + Qn               (bf16 out)   nwg = 1024
    gemm_bt_kernel<<<dim3(4, 256), 256, 0, stream>>>(QK + 512, 1024, BtP, bp, QK, 1024, T, nullptr, 512, 512);
    // out = T @ wf + bf                   (fp32 out)   nwg = 1024
    gemm_bt_kernel<<<dim3(4, 256), 256, 0, stream>>>(T, 512, BtF, bf, nullptr, 0, nullptr, (float*)d_out, 512, 512);
}